// Round 6
// baseline (5095.028 us; speedup 1.0000x reference)
//
#include <hip/hip_runtime.h>
#include <math.h>

#define B_   256
#define S_   160
#define E_   300
#define H_   256
#define T_   200
#define G4H  1024
#define CH   16
#define NCH  10

typedef float  f32x4  __attribute__((ext_vector_type(4)));
typedef __bf16 bf16x4 __attribute__((ext_vector_type(4)));
typedef __bf16 bf16x8 __attribute__((ext_vector_type(8)));

__device__ __forceinline__ float sigf(float x) {
    float e = expf(-fabsf(x));
    float p = 1.0f / (1.0f + e);
    return x >= 0.0f ? p : e * p;
}

// permuted gate-col order: n' = (j>>4)*64 + g*16 + (j&15); orig row for n':
__device__ __forceinline__ int norig(int np) {
    return ((np >> 4) & 3) * 256 + ((np >> 6) << 4) + (np & 15);
}

// 4 consecutive K-values from concatenated [first(300) | second(200) | pad] row
__device__ __forceinline__ float4 pick4(const float* __restrict__ e,
                                        const float* __restrict__ k, int kg) {
    if (kg < E_)      return *(const float4*)(e + kg);
    if (kg < E_ + T_) return *(const float4*)(k + (kg - E_));
    return make_float4(0.f, 0.f, 0.f, 0.f);
}

__device__ __forceinline__ void split4(float4 v, bf16x4& h, bf16x4& l) {
    h[0] = (__bf16)v.x; l[0] = (__bf16)(v.x - (float)h[0]);
    h[1] = (__bf16)v.y; l[1] = (__bf16)(v.y - (float)h[1]);
    h[2] = (__bf16)v.z; l[2] = (__bf16)(v.z - (float)h[2]);
    h[3] = (__bf16)v.w; l[3] = (__bf16)(v.w - (float)h[3]);
}

// ---------------------------------------------------------------------------
// Input GEMM (round-4 structure, no prefetch): split-bf16 MFMA, 128x128, BK=32.
// B rows / bg / output cols use the permuted n' ordering (gate-per-lane later).
// ---------------------------------------------------------------------------
__global__ __launch_bounds__(256, 2) void gemm_g2(
    const int* __restrict__ x1, const int* __restrict__ x2,
    const float* __restrict__ key_c, const float* __restrict__ key_r,
    const float* __restrict__ emb, const float* __restrict__ Wih,
    const float* __restrict__ Wkh, const float* __restrict__ bg,
    float* __restrict__ G, int s0)
{
    __shared__ __align__(16) __bf16 Ah[128 * 32];
    __shared__ __align__(16) __bf16 Al[128 * 32];
    __shared__ __align__(16) __bf16 Bh[128 * 32];
    __shared__ __align__(16) __bf16 Bl[128 * 32];

    const int t   = threadIdx.x;
    const int rnn = blockIdx.z;
    const int m0  = blockIdx.x * 128;
    const int n0  = blockIdx.y * 128;
    const int* xx = rnn ? x2 : x1;
    const float* key = rnn ? key_r : key_c;

    const int r0  = t >> 3;
    const int kq  = t & 7;
    const int csw = (((kq >> 1) ^ ((r0 >> 1) & 3)) * 16) + (kq & 1) * 8;

    const float* aeb[4]; const float* akb[4];
    const float* wv1[4]; const float* wv2[4];
    #pragma unroll
    for (int i = 0; i < 4; ++i) {
        const int row = r0 + 32 * i;
        const int am  = m0 + row;
        const int bs  = (am >> 4) * S_ + s0 + (am & 15);
        aeb[i] = emb + (size_t)xx[bs] * E_;
        akb[i] = key + (size_t)bs * T_;
        const int no = norig(n0 + row);
        wv1[i] = Wih + (size_t)no * E_;
        wv2[i] = Wkh + (size_t)no * T_;
    }

    const int w  = t >> 6;
    const int wm = w >> 1;
    const int wn = w & 1;
    const int l  = t & 63;
    const int cl = l & 15;
    const int ch = l >> 4;
    const int chs = ((ch ^ ((cl >> 1) & 3)) * 16);

    f32x4 acc[4][4];
    #pragma unroll
    for (int fm = 0; fm < 4; ++fm)
        #pragma unroll
        for (int fn = 0; fn < 4; ++fn) acc[fm][fn] = (f32x4){0.f, 0.f, 0.f, 0.f};

    for (int kt = 0; kt < 16; ++kt) {
        const int kg = kt * 32 + kq * 4;
        bf16x4 sAh[4], sAl[4], sBh[4], sBl[4];
        #pragma unroll
        for (int i = 0; i < 4; ++i) {
            const float4 va = pick4(aeb[i], akb[i], kg);
            const float4 vb = pick4(wv1[i], wv2[i], kg);
            split4(va, sAh[i], sAl[i]);
            split4(vb, sBh[i], sBl[i]);
        }
        __syncthreads();
        #pragma unroll
        for (int i = 0; i < 4; ++i) {
            const int off = (r0 + 32 * i) * 64 + csw;
            *(bf16x4*)((char*)Ah + off) = sAh[i];
            *(bf16x4*)((char*)Al + off) = sAl[i];
            *(bf16x4*)((char*)Bh + off) = sBh[i];
            *(bf16x4*)((char*)Bl + off) = sBl[i];
        }
        __syncthreads();

        bf16x8 fBh[4], fBl[4];
        #pragma unroll
        for (int fn = 0; fn < 4; ++fn) {
            const int off = (wn * 64 + fn * 16 + cl) * 64 + chs;
            fBh[fn] = *(const bf16x8*)((const char*)Bh + off);
            fBl[fn] = *(const bf16x8*)((const char*)Bl + off);
        }
        #pragma unroll
        for (int fm = 0; fm < 4; ++fm) {
            const int off = (wm * 64 + fm * 16 + cl) * 64 + chs;
            const bf16x8 fAh = *(const bf16x8*)((const char*)Ah + off);
            const bf16x8 fAl = *(const bf16x8*)((const char*)Al + off);
            #pragma unroll
            for (int fn = 0; fn < 4; ++fn) {
                acc[fm][fn] = __builtin_amdgcn_mfma_f32_16x16x32_bf16(fAh, fBh[fn], acc[fm][fn], 0, 0, 0);
                acc[fm][fn] = __builtin_amdgcn_mfma_f32_16x16x32_bf16(fAh, fBl[fn], acc[fm][fn], 0, 0, 0);
                acc[fm][fn] = __builtin_amdgcn_mfma_f32_16x16x32_bf16(fAl, fBh[fn], acc[fm][fn], 0, 0, 0);
            }
        }
    }

    float bgl[4];
    #pragma unroll
    for (int fn = 0; fn < 4; ++fn) bgl[fn] = bg[norig(n0 + wn * 64 + fn * 16 + cl)];

    #pragma unroll
    for (int fm = 0; fm < 4; ++fm) {
        #pragma unroll
        for (int r = 0; r < 4; ++r) {
            const int m  = m0 + wm * 64 + fm * 16 + ch * 4 + r;
            const int b  = m >> 4;
            const int sl = m & 15;
            float* rowp = G + ((size_t)(rnn * CH + sl) * B_ + b) * G4H;
            #pragma unroll
            for (int fn = 0; fn < 4; ++fn)
                rowp[n0 + wn * 64 + fn * 16 + cl] = acc[fm][fn][r] + bgl[fn];
        }
    }
}

// ---------------------------------------------------------------------------
// Split Whh into bf16 hi/lo planes, rows stored in permuted n' order.
// ---------------------------------------------------------------------------
__global__ __launch_bounds__(64) void whh_split(
    const float* __restrict__ W, __bf16* __restrict__ hi, __bf16* __restrict__ lo)
{
    const int n  = blockIdx.x;                         // orig row: g*256 + j
    const int np = ((n & 255) >> 4) * 64 + (n >> 8) * 16 + (n & 15);
    const int k4 = threadIdx.x * 4;
    const float4 v = *(const float4*)(W + (size_t)n * 256 + k4);
    bf16x4 h, l;
    split4(v, h, l);
    *(bf16x4*)(hi + (size_t)np * 256 + k4) = h;
    *(bf16x4*)(lo + (size_t)np * 256 + k4) = l;
}

// ---------------------------------------------------------------------------
// 16 LSTM steps in ONE kernel. 128 blocks (16 mg x 8 jsl) x 256 thr, 1/CU,
// all resident. Block tile: M=32 (16 rnn0 + 16 rnn1 batch rows, sharing Whh)
// x N=128 n' (32 j x 4 gates). Wave (mf, jg) owns 16x64: all 4 gates of its
// cells are LANE-LOCAL (no transpose, no intra-step barrier). Whh hi+lo
// resident in 128KB LDS (swizzled frag layout). h ping-pongs in global fp32;
// c lives in registers for the whole chunk. Between steps: per-mg 8-block
// atomic barrier (slot per global step) + device fences.
// ---------------------------------------------------------------------------
__global__ __launch_bounds__(256, 1) void lstm_chunk(
    const float* __restrict__ G,
    const __bf16* __restrict__ Whi, const __bf16* __restrict__ Wlo,
    float* __restrict__ h0, float* __restrict__ h1,
    float* __restrict__ cst, float* __restrict__ sc,
    int* __restrict__ bar, int s_base, int first)
{
    __shared__ __align__(16) __bf16 Wlds[2 * 8 * 128 * 32];   // 128 KB

    const int t   = threadIdx.x;
    const int mg  = blockIdx.x >> 3;    // 0..15
    const int jsl = blockIdx.x & 7;     // 0..7
    const int w   = t >> 6;
    const int l   = t & 63;
    const int cl  = l & 15;
    const int ch  = l >> 4;
    const int mf  = w >> 1;             // rnn
    const int jg  = w & 1;

    // ---- stage W slice (128 n'-rows) into LDS, swizzled frag layout ----
    {
        const int row = t >> 1;             // 0..127
        const int kh  = (t & 1) * 128;
        const __bf16* s0p = Whi + (size_t)(jsl * 128 + row) * 256;
        const __bf16* s1p = Wlo + (size_t)(jsl * 128 + row) * 256;
        #pragma unroll
        for (int q = 0; q < 16; ++q) {
            const int k0 = kh + q * 8;
            const int ks = k0 >> 5;
            const int cc = ((k0 >> 3) & 3) ^ ((row >> 1) & 3);
            char* d = (char*)Wlds + (ks * 128 + row) * 64 + cc * 16;
            *(bf16x8*)d = *(const bf16x8*)(s0p + k0);
            *(bf16x8*)(d + 65536) = *(const bf16x8*)(s1p + k0);
        }
    }

    const int jb   = jsl * 32 + jg * 16 + cl;   // j column
    const int bloc = mg * 16;                   // batch base
    float c4[4];
    if (first) {
        c4[0] = c4[1] = c4[2] = c4[3] = 0.f;
    } else {
        #pragma unroll
        for (int r = 0; r < 4; ++r)
            c4[r] = cst[((size_t)(mf * 256) + bloc + ch * 4 + r) * 256 + jb];
    }
    __syncthreads();

    for (int s = 0; s < CH; ++s) {
        const float* hin  = (s & 1) ? h1 : h0;
        float*       hout = (s & 1) ? h0 : h1;

        // ---- A-frags: fp32 h -> split bf16 hi/lo (row = cl of this mf) ----
        bf16x8 fAh[8], fAl[8];
        const float* hrow = hin + ((size_t)(mf * 256) + bloc + cl) * 256;
        #pragma unroll
        for (int ks = 0; ks < 8; ++ks) {
            const float4 v0 = *(const float4*)(hrow + ks * 32 + ch * 8);
            const float4 v1 = *(const float4*)(hrow + ks * 32 + ch * 8 + 4);
            bf16x4 h0v, l0v, h1v, l1v;
            split4(v0, h0v, l0v);
            split4(v1, h1v, l1v);
            fAh[ks] = __builtin_shufflevector(h0v, h1v, 0, 1, 2, 3, 4, 5, 6, 7);
            fAl[ks] = __builtin_shufflevector(l0v, l1v, 0, 1, 2, 3, 4, 5, 6, 7);
        }

        // ---- G loads (issued early, consumed in epilogue) ----
        float Gv[4][4];
        const float* Gbase = G + (((size_t)(mf * CH + s) * B_) + bloc) * G4H
                           + jsl * 128 + jg * 64;
        #pragma unroll
        for (int g = 0; g < 4; ++g)
            #pragma unroll
            for (int r = 0; r < 4; ++r)
                Gv[g][r] = Gbase[(size_t)(ch * 4 + r) * G4H + g * 16 + cl];

        // ---- MFMA: 8 ksub x (4 gates x 3 split passes) ----
        f32x4 accA[4], accB[4];
        #pragma unroll
        for (int g = 0; g < 4; ++g) {
            accA[g] = (f32x4){0.f, 0.f, 0.f, 0.f};
            accB[g] = (f32x4){0.f, 0.f, 0.f, 0.f};
        }
        #pragma unroll
        for (int ks = 0; ks < 8; ++ks) {
            bf16x8 fBh[4], fBl[4];
            #pragma unroll
            for (int g = 0; g < 4; ++g) {
                const int row = jg * 64 + g * 16 + cl;
                const char* base = (const char*)Wlds + (ks * 128 + row) * 64
                                 + ((ch ^ ((row >> 1) & 3)) * 16);
                fBh[g] = *(const bf16x8*)(base);
                fBl[g] = *(const bf16x8*)(base + 65536);
            }
            #pragma unroll
            for (int g = 0; g < 4; ++g)
                accA[g] = __builtin_amdgcn_mfma_f32_16x16x32_bf16(fAh[ks], fBh[g], accA[g], 0, 0, 0);
            #pragma unroll
            for (int g = 0; g < 4; ++g)
                accB[g] = __builtin_amdgcn_mfma_f32_16x16x32_bf16(fAh[ks], fBl[g], accB[g], 0, 0, 0);
            #pragma unroll
            for (int g = 0; g < 4; ++g)
                accA[g] = __builtin_amdgcn_mfma_f32_16x16x32_bf16(fAl[ks], fBh[g], accA[g], 0, 0, 0);
        }

        // ---- lane-local gate math + state update ----
        #pragma unroll
        for (int r = 0; r < 4; ++r) {
            const float gi = accA[0][r] + accB[0][r] + Gv[0][r];
            const float gf = accA[1][r] + accB[1][r] + Gv[1][r];
            const float gg = accA[2][r] + accB[2][r] + Gv[2][r];
            const float go = accA[3][r] + accB[3][r] + Gv[3][r];
            const float c = sigf(gf) * c4[r] + sigf(gi) * tanhf(gg);
            const float h = sigf(go) * tanhf(c);
            c4[r] = c;
            const int brow = bloc + ch * 4 + r;
            hout[((size_t)(mf * 256) + brow) * 256 + jb] = h;
            if (mf == 0) sc[((size_t)brow * S_ + s_base + s) * H_ + jb] = h;
        }

        // ---- inter-block barrier (8 blocks of this mg) ----
        if (s < CH - 1) {
            __threadfence();
            __syncthreads();
            if (t == 0) {
                const int slot = (s_base + s) * 16 + mg;
                atomicAdd(&bar[slot], 1);
                while (__hip_atomic_load(&bar[slot], __ATOMIC_ACQUIRE,
                                         __HIP_MEMORY_SCOPE_AGENT) < 8)
                    __builtin_amdgcn_s_sleep(1);
            }
            __syncthreads();
            __threadfence();
        }
    }

    #pragma unroll
    for (int r = 0; r < 4; ++r)
        cst[((size_t)(mf * 256) + bloc + ch * 4 + r) * 256 + jb] = c4[r];
}

// ---------------------------------------------------------------------------
// Fused attention epilogue, one block per batch row b. r = final rnn1 h (fp32).
// ---------------------------------------------------------------------------
__global__ __launch_bounds__(256) void final_kernel(
    const float* __restrict__ sc, const float* __restrict__ r,
    const float* __restrict__ Wattn, const float* __restrict__ battn,
    const float* __restrict__ M, const float* __restrict__ bscal,
    const float* __restrict__ mask, float* __restrict__ out)
{
    __shared__ float rs[256], us[256], red[256], as_[256];
    const int b = blockIdx.x;
    const int t = threadIdx.x;

    rs[t] = r[(size_t)b * 256 + t];
    __syncthreads();

    float acc = 0.0f;
    for (int h = 0; h < 256; ++h) acc += rs[h] * Wattn[h * 256 + t];
    us[t] = acc;

    red[t] = battn[t] * rs[t];
    __syncthreads();
    for (int off = 128; off; off >>= 1) {
        if (t < off) red[t] += red[t + off];
        __syncthreads();
    }
    float beta = red[0];
    __syncthreads();

    float vh = 0.0f;
    {
        const float* Mrow = M + t * 256;
        for (int k = 0; k < 256; ++k) vh += Mrow[k] * rs[k];
    }

    float e = -INFINITY;
    if (t < S_) {
        float d = 0.0f;
        const float* scrow = sc + ((size_t)b * S_ + t) * H_;
        for (int h = 0; h < 256; ++h) d += scrow[h] * us[h];
        e = (d + beta) * mask[b * S_ + t];
    }
    red[t] = e;
    __syncthreads();
    for (int off = 128; off; off >>= 1) {
        if (t < off) red[t] = fmaxf(red[t], red[t + off]);
        __syncthreads();
    }
    float mx = red[0];
    __syncthreads();

    float p = (t < S_) ? expf(e - mx) : 0.0f;
    as_[t] = p;
    red[t] = p;
    __syncthreads();
    for (int off = 128; off; off >>= 1) {
        if (t < off) red[t] += red[t + off];
        __syncthreads();
    }
    float inv = 1.0f / red[0];
    __syncthreads();

    float ca = 0.0f;
    for (int s = 0; s < S_; ++s) ca += as_[s] * sc[((size_t)b * S_ + s) * H_ + t];
    ca *= inv;

    red[t] = ca * vh;
    __syncthreads();
    for (int off = 128; off; off >>= 1) {
        if (t < off) red[t] += red[t + off];
        __syncthreads();
    }
    if (t == 0) out[b] = red[0] + bscal[0];
}

// ---------------------------------------------------------------------------
extern "C" void kernel_launch(void* const* d_in, const int* in_sizes, int n_in,
                              void* d_out, int out_size, void* d_ws, size_t ws_size,
                              hipStream_t stream)
{
    const int*   x1    = (const int*)d_in[0];
    const int*   x2    = (const int*)d_in[1];
    const float* mask  = (const float*)d_in[2];
    const float* key_c = (const float*)d_in[3];
    const float* key_r = (const float*)d_in[4];
    const float* emb   = (const float*)d_in[5];
    const float* Wih   = (const float*)d_in[6];
    const float* Whh   = (const float*)d_in[7];
    const float* Wkh   = (const float*)d_in[8];
    const float* bg    = (const float*)d_in[9];
    const float* Wattn = (const float*)d_in[10];
    const float* battn = (const float*)d_in[11];
    const float* M     = (const float*)d_in[12];
    const float* bb    = (const float*)d_in[13];
    float* out = (float*)d_out;
    char*  wsb = (char*)d_ws;

    // byte layout
    float*  G    = (float*)(wsb + 0);            // 33,554,432
    float*  sc   = (float*)(wsb + 33554432);     // 41,943,040
    float*  h0   = (float*)(wsb + 75497472);     //    524,288
    float*  h1   = (float*)(wsb + 76021760);     //    524,288
    float*  cst  = (float*)(wsb + 76546048);     //    524,288
    __bf16* Whi  = (__bf16*)(wsb + 77070336);    //    524,288
    __bf16* Wlo  = (__bf16*)(wsb + 77594624);    //    524,288
    int*    bar  = (int*)(wsb + 78118912);       //     10,240
    if (ws_size < 78129152) return;  // fail visibly if workspace too small

    hipMemsetAsync(h0, 0, 524288, stream);
    hipMemsetAsync(bar, 0, 10240, stream);
    whh_split<<<dim3(1024), 64, 0, stream>>>(Whh, Whi, Wlo);

    for (int ci = 0; ci < NCH; ++ci) {
        gemm_g2<<<dim3(32, 8, 2), 256, 0, stream>>>(x1, x2, key_c, key_r, emb,
                                                    Wih, Wkh, bg, G, ci * CH);
        lstm_chunk<<<dim3(128), 256, 0, stream>>>(G, Whi, Wlo, h0, h1, cst, sc,
                                                  bar, ci * CH, ci == 0);
    }

    // 160 steps (even) -> final h is in h0; r = rnn1 rows
    final_kernel<<<dim3(256), 256, 0, stream>>>(sc, h0 + 65536, Wattn, battn,
                                                M, bb, mask, out);
}

// Round 7
// 4864.531 us; speedup vs baseline: 1.0474x; 1.0474x over previous
//
#include <hip/hip_runtime.h>
#include <math.h>

#define B_   256
#define S_   160
#define E_   300
#define H_   256
#define T_   200
#define G4H  1024
#define CH   16
#define NCH  10

typedef float  f32x4  __attribute__((ext_vector_type(4)));
typedef __bf16 bf16x4 __attribute__((ext_vector_type(4)));
typedef __bf16 bf16x8 __attribute__((ext_vector_type(8)));

__device__ __forceinline__ float sigf(float x) {
    float e = expf(-fabsf(x));
    float p = 1.0f / (1.0f + e);
    return x >= 0.0f ? p : e * p;
}

// permuted gate-col order: n' = (j>>4)*64 + g*16 + (j&15); orig row for n':
__device__ __forceinline__ int norig(int np) {
    return ((np >> 4) & 3) * 256 + ((np >> 6) << 4) + (np & 15);
}

// 4 consecutive K-values from concatenated [first(300) | second(200) | pad] row
__device__ __forceinline__ float4 pick4(const float* __restrict__ e,
                                        const float* __restrict__ k, int kg) {
    if (kg < E_)      return *(const float4*)(e + kg);
    if (kg < E_ + T_) return *(const float4*)(k + (kg - E_));
    return make_float4(0.f, 0.f, 0.f, 0.f);
}

__device__ __forceinline__ void split4(float4 v, bf16x4& h, bf16x4& l) {
    h[0] = (__bf16)v.x; l[0] = (__bf16)(v.x - (float)h[0]);
    h[1] = (__bf16)v.y; l[1] = (__bf16)(v.y - (float)h[1]);
    h[2] = (__bf16)v.z; l[2] = (__bf16)(v.z - (float)h[2]);
    h[3] = (__bf16)v.w; l[3] = (__bf16)(v.w - (float)h[3]);
}

// ---------------------------------------------------------------------------
// Input GEMM: split-bf16 MFMA, 128x128, BK=32. Outputs in permuted n' order.
// launch_bounds (256,4): 4 blocks/CU (was 2 -> occupancy 21%).
// ---------------------------------------------------------------------------
__global__ __launch_bounds__(256, 4) void gemm_g2(
    const int* __restrict__ x1, const int* __restrict__ x2,
    const float* __restrict__ key_c, const float* __restrict__ key_r,
    const float* __restrict__ emb, const float* __restrict__ Wih,
    const float* __restrict__ Wkh, const float* __restrict__ bg,
    float* __restrict__ G, int s0)
{
    __shared__ __align__(16) __bf16 Ah[128 * 32];
    __shared__ __align__(16) __bf16 Al[128 * 32];
    __shared__ __align__(16) __bf16 Bh[128 * 32];
    __shared__ __align__(16) __bf16 Bl[128 * 32];

    const int t   = threadIdx.x;
    const int rnn = blockIdx.z;
    const int m0  = blockIdx.x * 128;
    const int n0  = blockIdx.y * 128;
    const int* xx = rnn ? x2 : x1;
    const float* key = rnn ? key_r : key_c;

    const int r0  = t >> 3;
    const int kq  = t & 7;
    const int csw = (((kq >> 1) ^ ((r0 >> 1) & 3)) * 16) + (kq & 1) * 8;

    const float* aeb[4]; const float* akb[4];
    const float* wv1[4]; const float* wv2[4];
    #pragma unroll
    for (int i = 0; i < 4; ++i) {
        const int row = r0 + 32 * i;
        const int am  = m0 + row;
        const int bs  = (am >> 4) * S_ + s0 + (am & 15);
        aeb[i] = emb + (size_t)xx[bs] * E_;
        akb[i] = key + (size_t)bs * T_;
        const int no = norig(n0 + row);
        wv1[i] = Wih + (size_t)no * E_;
        wv2[i] = Wkh + (size_t)no * T_;
    }

    const int w  = t >> 6;
    const int wm = w >> 1;
    const int wn = w & 1;
    const int l  = t & 63;
    const int cl = l & 15;
    const int ch = l >> 4;
    const int chs = ((ch ^ ((cl >> 1) & 3)) * 16);

    f32x4 acc[4][4];
    #pragma unroll
    for (int fm = 0; fm < 4; ++fm)
        #pragma unroll
        for (int fn = 0; fn < 4; ++fn) acc[fm][fn] = (f32x4){0.f, 0.f, 0.f, 0.f};

    for (int kt = 0; kt < 16; ++kt) {
        const int kg = kt * 32 + kq * 4;
        bf16x4 sAh[4], sAl[4], sBh[4], sBl[4];
        #pragma unroll
        for (int i = 0; i < 4; ++i) {
            const float4 va = pick4(aeb[i], akb[i], kg);
            const float4 vb = pick4(wv1[i], wv2[i], kg);
            split4(va, sAh[i], sAl[i]);
            split4(vb, sBh[i], sBl[i]);
        }
        __syncthreads();
        #pragma unroll
        for (int i = 0; i < 4; ++i) {
            const int off = (r0 + 32 * i) * 64 + csw;
            *(bf16x4*)((char*)Ah + off) = sAh[i];
            *(bf16x4*)((char*)Al + off) = sAl[i];
            *(bf16x4*)((char*)Bh + off) = sBh[i];
            *(bf16x4*)((char*)Bl + off) = sBl[i];
        }
        __syncthreads();

        bf16x8 fBh[4], fBl[4];
        #pragma unroll
        for (int fn = 0; fn < 4; ++fn) {
            const int off = (wn * 64 + fn * 16 + cl) * 64 + chs;
            fBh[fn] = *(const bf16x8*)((const char*)Bh + off);
            fBl[fn] = *(const bf16x8*)((const char*)Bl + off);
        }
        #pragma unroll
        for (int fm = 0; fm < 4; ++fm) {
            const int off = (wm * 64 + fm * 16 + cl) * 64 + chs;
            const bf16x8 fAh = *(const bf16x8*)((const char*)Ah + off);
            const bf16x8 fAl = *(const bf16x8*)((const char*)Al + off);
            #pragma unroll
            for (int fn = 0; fn < 4; ++fn) {
                acc[fm][fn] = __builtin_amdgcn_mfma_f32_16x16x32_bf16(fAh, fBh[fn], acc[fm][fn], 0, 0, 0);
                acc[fm][fn] = __builtin_amdgcn_mfma_f32_16x16x32_bf16(fAh, fBl[fn], acc[fm][fn], 0, 0, 0);
                acc[fm][fn] = __builtin_amdgcn_mfma_f32_16x16x32_bf16(fAl, fBh[fn], acc[fm][fn], 0, 0, 0);
            }
        }
    }

    float bgl[4];
    #pragma unroll
    for (int fn = 0; fn < 4; ++fn) bgl[fn] = bg[norig(n0 + wn * 64 + fn * 16 + cl)];

    #pragma unroll
    for (int fm = 0; fm < 4; ++fm) {
        #pragma unroll
        for (int r = 0; r < 4; ++r) {
            const int m  = m0 + wm * 64 + fm * 16 + ch * 4 + r;
            const int b  = m >> 4;
            const int sl = m & 15;
            float* rowp = G + ((size_t)(rnn * CH + sl) * B_ + b) * G4H;
            #pragma unroll
            for (int fn = 0; fn < 4; ++fn)
                rowp[n0 + wn * 64 + fn * 16 + cl] = acc[fm][fn][r] + bgl[fn];
        }
    }
}

// ---------------------------------------------------------------------------
// Split Whh into bf16 hi/lo planes, rows stored in permuted n' order.
// ---------------------------------------------------------------------------
__global__ __launch_bounds__(64) void whh_split(
    const float* __restrict__ W, __bf16* __restrict__ hi, __bf16* __restrict__ lo)
{
    const int n  = blockIdx.x;                         // orig row: g*256 + j
    const int np = ((n & 255) >> 4) * 64 + (n >> 8) * 16 + (n & 15);
    const int k4 = threadIdx.x * 4;
    const float4 v = *(const float4*)(W + (size_t)n * 256 + k4);
    bf16x4 h, l;
    split4(v, h, l);
    *(bf16x4*)(hi + (size_t)np * 256 + k4) = h;
    *(bf16x4*)(lo + (size_t)np * 256 + k4) = l;
}

// ---------------------------------------------------------------------------
// 16 LSTM steps, ONE kernel, NO cross-block sync. 32 blocks x 512 thr (8
// waves). Block = (rnn, 16 batch rows) x ALL 1024 n' cols -> h for its rows
// is produced entirely in-block; steps separated by one __syncthreads, h
// ping-pongs in LDS (fp32, stride 260 = conflict-free frag reads). Whh hi/lo
// (1 MB) streams from L2 each step directly into MFMA B-fragments. Wave w
// owns n' [w*128,(w+1)*128) = 2 j-groups x 4 gates -> gate math lane-local.
// c lives in registers across all 16 steps; h/c persisted to global at chunk
// boundaries only.
// ---------------------------------------------------------------------------
__global__ __launch_bounds__(512, 2) void lstm_chunk(
    const float* __restrict__ G,
    const __bf16* __restrict__ Whi, const __bf16* __restrict__ Wlo,
    float* __restrict__ hbuf, float* __restrict__ cst,
    float* __restrict__ sc, int s_base, int first)
{
    __shared__ __align__(16) float hA[2][16][260];

    const int t   = threadIdx.x;
    const int w   = t >> 6;            // wave 0..7
    const int l   = t & 63;
    const int cl  = l & 15;
    const int ch  = l >> 4;            // 0..3
    const int bid = blockIdx.x;        // 0..31
    const int rnn = bid >> 4;
    const int b0  = (bid & 15) * 16;
    const int mrow0 = rnn * 256 + b0;

    // ---- load chunk-start h into hA[0] ----
    {
        const int row = t >> 5;        // 0..15
        const int c8  = t & 31;        // 8-float chunk
        const float* src = hbuf + (size_t)(mrow0 + row) * 256 + c8 * 8;
        *(float4*)&hA[0][row][c8 * 8]     = *(const float4*)(src);
        *(float4*)&hA[0][row][c8 * 8 + 4] = *(const float4*)(src + 4);
    }

    // ---- c state: 8 cells/lane: (jg 0..1, r 0..3) ----
    float cv[2][4];
    if (first) {
        #pragma unroll
        for (int jg = 0; jg < 2; ++jg)
            #pragma unroll
            for (int r = 0; r < 4; ++r) cv[jg][r] = 0.f;
    } else {
        #pragma unroll
        for (int jg = 0; jg < 2; ++jg)
            #pragma unroll
            for (int r = 0; r < 4; ++r)
                cv[jg][r] = cst[(size_t)(mrow0 + ch * 4 + r) * 256
                                + (w * 2 + jg) * 16 + cl];
    }
    __syncthreads();

    for (int s = 0; s < CH; ++s) {
        const int p = s & 1;

        // ---- A-frags: LDS fp32 h -> split bf16 hi/lo ----
        bf16x8 fAh[8], fAl[8];
        #pragma unroll
        for (int ks = 0; ks < 8; ++ks) {
            const float4 v0 = *(const float4*)&hA[p][cl][ks * 32 + ch * 8];
            const float4 v1 = *(const float4*)&hA[p][cl][ks * 32 + ch * 8 + 4];
            bf16x4 h0v, l0v, h1v, l1v;
            split4(v0, h0v, l0v);
            split4(v1, h1v, l1v);
            fAh[ks] = __builtin_shufflevector(h0v, h1v, 0, 1, 2, 3, 4, 5, 6, 7);
            fAl[ks] = __builtin_shufflevector(l0v, l1v, 0, 1, 2, 3, 4, 5, 6, 7);
        }

        // ---- G loads (independent; issue early) ----
        float Gv[2][4][4];
        const float* Gb = G + ((size_t)(rnn * CH + s) * B_ + b0) * G4H;
        #pragma unroll
        for (int jg = 0; jg < 2; ++jg)
            #pragma unroll
            for (int g = 0; g < 4; ++g)
                #pragma unroll
                for (int r = 0; r < 4; ++r)
                    Gv[jg][g][r] = Gb[(size_t)(ch * 4 + r) * G4H
                                      + (w * 2 + jg) * 64 + g * 16 + cl];

        // ---- MFMA: B streamed straight from global (L2-resident W) ----
        f32x4 acc[2][4];
        #pragma unroll
        for (int jg = 0; jg < 2; ++jg)
            #pragma unroll
            for (int g = 0; g < 4; ++g) acc[jg][g] = (f32x4){0.f, 0.f, 0.f, 0.f};

        #pragma unroll
        for (int ks = 0; ks < 8; ++ks) {
            bf16x8 fBh[2][4], fBl[2][4];
            #pragma unroll
            for (int jg = 0; jg < 2; ++jg)
                #pragma unroll
                for (int g = 0; g < 4; ++g) {
                    const size_t off = (size_t)((w * 2 + jg) * 64 + g * 16 + cl) * 256
                                     + ks * 32 + ch * 8;
                    fBh[jg][g] = *(const bf16x8*)(Whi + off);
                    fBl[jg][g] = *(const bf16x8*)(Wlo + off);
                }
            #pragma unroll
            for (int jg = 0; jg < 2; ++jg)
                #pragma unroll
                for (int g = 0; g < 4; ++g) {
                    acc[jg][g] = __builtin_amdgcn_mfma_f32_16x16x32_bf16(fAh[ks], fBh[jg][g], acc[jg][g], 0, 0, 0);
                    acc[jg][g] = __builtin_amdgcn_mfma_f32_16x16x32_bf16(fAh[ks], fBl[jg][g], acc[jg][g], 0, 0, 0);
                    acc[jg][g] = __builtin_amdgcn_mfma_f32_16x16x32_bf16(fAl[ks], fBh[jg][g], acc[jg][g], 0, 0, 0);
                }
        }

        // ---- lane-local gate math, h -> LDS (other buffer) + sc ----
        #pragma unroll
        for (int jg = 0; jg < 2; ++jg) {
            const int j = (w * 2 + jg) * 16 + cl;
            #pragma unroll
            for (int r = 0; r < 4; ++r) {
                const float gi = acc[jg][0][r] + Gv[jg][0][r];
                const float gf = acc[jg][1][r] + Gv[jg][1][r];
                const float gg = acc[jg][2][r] + Gv[jg][2][r];
                const float go = acc[jg][3][r] + Gv[jg][3][r];
                const float c = sigf(gf) * cv[jg][r] + sigf(gi) * tanhf(gg);
                const float h = sigf(go) * tanhf(c);
                cv[jg][r] = c;
                const int row = ch * 4 + r;
                hA[p ^ 1][row][j] = h;
                if (rnn == 0)
                    sc[((size_t)(b0 + row) * S_ + s_base + s) * H_ + j] = h;
                if (s == CH - 1)
                    hbuf[(size_t)(mrow0 + row) * 256 + j] = h;
            }
        }
        __syncthreads();
    }

    // ---- persist c ----
    #pragma unroll
    for (int jg = 0; jg < 2; ++jg)
        #pragma unroll
        for (int r = 0; r < 4; ++r)
            cst[(size_t)(mrow0 + ch * 4 + r) * 256 + (w * 2 + jg) * 16 + cl]
                = cv[jg][r];
}

// ---------------------------------------------------------------------------
// Fused attention epilogue, one block per batch row b. r = final rnn1 h.
// ---------------------------------------------------------------------------
__global__ __launch_bounds__(256) void final_kernel(
    const float* __restrict__ sc, const float* __restrict__ r,
    const float* __restrict__ Wattn, const float* __restrict__ battn,
    const float* __restrict__ M, const float* __restrict__ bscal,
    const float* __restrict__ mask, float* __restrict__ out)
{
    __shared__ float rs[256], us[256], red[256], as_[256];
    const int b = blockIdx.x;
    const int t = threadIdx.x;

    rs[t] = r[(size_t)b * 256 + t];
    __syncthreads();

    float acc = 0.0f;
    for (int h = 0; h < 256; ++h) acc += rs[h] * Wattn[h * 256 + t];
    us[t] = acc;

    red[t] = battn[t] * rs[t];
    __syncthreads();
    for (int off = 128; off; off >>= 1) {
        if (t < off) red[t] += red[t + off];
        __syncthreads();
    }
    float beta = red[0];
    __syncthreads();

    float vh = 0.0f;
    {
        const float* Mrow = M + t * 256;
        for (int k = 0; k < 256; ++k) vh += Mrow[k] * rs[k];
    }

    float e = -INFINITY;
    if (t < S_) {
        float d = 0.0f;
        const float* scrow = sc + ((size_t)b * S_ + t) * H_;
        for (int h = 0; h < 256; ++h) d += scrow[h] * us[h];
        e = (d + beta) * mask[b * S_ + t];
    }
    red[t] = e;
    __syncthreads();
    for (int off = 128; off; off >>= 1) {
        if (t < off) red[t] = fmaxf(red[t], red[t + off]);
        __syncthreads();
    }
    float mx = red[0];
    __syncthreads();

    float p = (t < S_) ? expf(e - mx) : 0.0f;
    as_[t] = p;
    red[t] = p;
    __syncthreads();
    for (int off = 128; off; off >>= 1) {
        if (t < off) red[t] += red[t + off];
        __syncthreads();
    }
    float inv = 1.0f / red[0];
    __syncthreads();

    float ca = 0.0f;
    for (int s = 0; s < S_; ++s) ca += as_[s] * sc[((size_t)b * S_ + s) * H_ + t];
    ca *= inv;

    red[t] = ca * vh;
    __syncthreads();
    for (int off = 128; off; off >>= 1) {
        if (t < off) red[t] += red[t + off];
        __syncthreads();
    }
    if (t == 0) out[b] = red[0] + bscal[0];
}

// ---------------------------------------------------------------------------
extern "C" void kernel_launch(void* const* d_in, const int* in_sizes, int n_in,
                              void* d_out, int out_size, void* d_ws, size_t ws_size,
                              hipStream_t stream)
{
    const int*   x1    = (const int*)d_in[0];
    const int*   x2    = (const int*)d_in[1];
    const float* mask  = (const float*)d_in[2];
    const float* key_c = (const float*)d_in[3];
    const float* key_r = (const float*)d_in[4];
    const float* emb   = (const float*)d_in[5];
    const float* Wih   = (const float*)d_in[6];
    const float* Whh   = (const float*)d_in[7];
    const float* Wkh   = (const float*)d_in[8];
    const float* bg    = (const float*)d_in[9];
    const float* Wattn = (const float*)d_in[10];
    const float* battn = (const float*)d_in[11];
    const float* M     = (const float*)d_in[12];
    const float* bb    = (const float*)d_in[13];
    float* out = (float*)d_out;
    char*  wsb = (char*)d_ws;

    // byte layout
    float*  G    = (float*)(wsb + 0);            // 33,554,432
    float*  sc   = (float*)(wsb + 33554432);     // 41,943,040
    float*  hbuf = (float*)(wsb + 75497472);     //    524,288
    float*  cst  = (float*)(wsb + 76021760);     //    524,288
    __bf16* Whi  = (__bf16*)(wsb + 76546048);    //    524,288
    __bf16* Wlo  = (__bf16*)(wsb + 77070336);    //    524,288
    if (ws_size < 77594624) return;  // fail visibly if workspace too small

    hipMemsetAsync(hbuf, 0, 524288, stream);
    whh_split<<<dim3(1024), 64, 0, stream>>>(Whh, Whi, Wlo);

    for (int ci = 0; ci < NCH; ++ci) {
        gemm_g2<<<dim3(32, 8, 2), 256, 0, stream>>>(x1, x2, key_c, key_r, emb,
                                                    Wih, Wkh, bg, G, ci * CH);
        lstm_chunk<<<dim3(32), 512, 0, stream>>>(G, Whi, Wlo, hbuf, cst, sc,
                                                 ci * CH, ci == 0);
    }

    // r = final rnn1 h rows
    final_kernel<<<dim3(256), 256, 0, stream>>>(sc, hbuf + 65536, Wattn, battn,
                                                M, bb, mask, out);
}

// Round 8
// 1835.832 us; speedup vs baseline: 2.7753x; 2.6498x over previous
//
#include <hip/hip_runtime.h>
#include <math.h>

#define B_   256
#define S_   160
#define E_   300
#define H_   256
#define T_   200
#define G4H  1024
#define CH   16
#define NCH  10

typedef float  f32x4  __attribute__((ext_vector_type(4)));
typedef __bf16 bf16x4 __attribute__((ext_vector_type(4)));
typedef __bf16 bf16x8 __attribute__((ext_vector_type(8)));

__device__ __forceinline__ float sigf(float x) {
    float e = expf(-fabsf(x));
    float p = 1.0f / (1.0f + e);
    return x >= 0.0f ? p : e * p;
}

// permuted gate-col order: n' = (j>>4)*64 + g*16 + (j&15); orig row for n':
__device__ __forceinline__ int norig(int np) {
    return ((np >> 4) & 3) * 256 + ((np >> 6) << 4) + (np & 15);
}

// 4 consecutive K-values from concatenated [first(300) | second(200) | pad] row
__device__ __forceinline__ float4 pick4(const float* __restrict__ e,
                                        const float* __restrict__ k, int kg) {
    if (kg < E_)      return *(const float4*)(e + kg);
    if (kg < E_ + T_) return *(const float4*)(k + (kg - E_));
    return make_float4(0.f, 0.f, 0.f, 0.f);
}

__device__ __forceinline__ void split4(float4 v, bf16x4& h, bf16x4& l) {
    h[0] = (__bf16)v.x; l[0] = (__bf16)(v.x - (float)h[0]);
    h[1] = (__bf16)v.y; l[1] = (__bf16)(v.y - (float)h[1]);
    h[2] = (__bf16)v.z; l[2] = (__bf16)(v.z - (float)h[2]);
    h[3] = (__bf16)v.w; l[3] = (__bf16)(v.w - (float)h[3]);
}

// ---------------------------------------------------------------------------
// Input GEMM: split-bf16 MFMA, 128x128, BK=32. Outputs in permuted n' order.
// ---------------------------------------------------------------------------
__global__ __launch_bounds__(256, 4) void gemm_g2(
    const int* __restrict__ x1, const int* __restrict__ x2,
    const float* __restrict__ key_c, const float* __restrict__ key_r,
    const float* __restrict__ emb, const float* __restrict__ Wih,
    const float* __restrict__ Wkh, const float* __restrict__ bg,
    float* __restrict__ G, int s0)
{
    __shared__ __align__(16) __bf16 Ah[128 * 32];
    __shared__ __align__(16) __bf16 Al[128 * 32];
    __shared__ __align__(16) __bf16 Bh[128 * 32];
    __shared__ __align__(16) __bf16 Bl[128 * 32];

    const int t   = threadIdx.x;
    const int rnn = blockIdx.z;
    const int m0  = blockIdx.x * 128;
    const int n0  = blockIdx.y * 128;
    const int* xx = rnn ? x2 : x1;
    const float* key = rnn ? key_r : key_c;

    const int r0  = t >> 3;
    const int kq  = t & 7;
    const int csw = (((kq >> 1) ^ ((r0 >> 1) & 3)) * 16) + (kq & 1) * 8;

    const float* aeb[4]; const float* akb[4];
    const float* wv1[4]; const float* wv2[4];
    #pragma unroll
    for (int i = 0; i < 4; ++i) {
        const int row = r0 + 32 * i;
        const int am  = m0 + row;
        const int bs  = (am >> 4) * S_ + s0 + (am & 15);
        aeb[i] = emb + (size_t)xx[bs] * E_;
        akb[i] = key + (size_t)bs * T_;
        const int no = norig(n0 + row);
        wv1[i] = Wih + (size_t)no * E_;
        wv2[i] = Wkh + (size_t)no * T_;
    }

    const int w  = t >> 6;
    const int wm = w >> 1;
    const int wn = w & 1;
    const int l  = t & 63;
    const int cl = l & 15;
    const int ch = l >> 4;
    const int chs = ((ch ^ ((cl >> 1) & 3)) * 16);

    f32x4 acc[4][4];
    #pragma unroll
    for (int fm = 0; fm < 4; ++fm)
        #pragma unroll
        for (int fn = 0; fn < 4; ++fn) acc[fm][fn] = (f32x4){0.f, 0.f, 0.f, 0.f};

    for (int kt = 0; kt < 16; ++kt) {
        const int kg = kt * 32 + kq * 4;
        bf16x4 sAh[4], sAl[4], sBh[4], sBl[4];
        #pragma unroll
        for (int i = 0; i < 4; ++i) {
            const float4 va = pick4(aeb[i], akb[i], kg);
            const float4 vb = pick4(wv1[i], wv2[i], kg);
            split4(va, sAh[i], sAl[i]);
            split4(vb, sBh[i], sBl[i]);
        }
        __syncthreads();
        #pragma unroll
        for (int i = 0; i < 4; ++i) {
            const int off = (r0 + 32 * i) * 64 + csw;
            *(bf16x4*)((char*)Ah + off) = sAh[i];
            *(bf16x4*)((char*)Al + off) = sAl[i];
            *(bf16x4*)((char*)Bh + off) = sBh[i];
            *(bf16x4*)((char*)Bl + off) = sBl[i];
        }
        __syncthreads();

        bf16x8 fBh[4], fBl[4];
        #pragma unroll
        for (int fn = 0; fn < 4; ++fn) {
            const int off = (wn * 64 + fn * 16 + cl) * 64 + chs;
            fBh[fn] = *(const bf16x8*)((const char*)Bh + off);
            fBl[fn] = *(const bf16x8*)((const char*)Bl + off);
        }
        #pragma unroll
        for (int fm = 0; fm < 4; ++fm) {
            const int off = (wm * 64 + fm * 16 + cl) * 64 + chs;
            const bf16x8 fAh = *(const bf16x8*)((const char*)Ah + off);
            const bf16x8 fAl = *(const bf16x8*)((const char*)Al + off);
            #pragma unroll
            for (int fn = 0; fn < 4; ++fn) {
                acc[fm][fn] = __builtin_amdgcn_mfma_f32_16x16x32_bf16(fAh, fBh[fn], acc[fm][fn], 0, 0, 0);
                acc[fm][fn] = __builtin_amdgcn_mfma_f32_16x16x32_bf16(fAh, fBl[fn], acc[fm][fn], 0, 0, 0);
                acc[fm][fn] = __builtin_amdgcn_mfma_f32_16x16x32_bf16(fAl, fBh[fn], acc[fm][fn], 0, 0, 0);
            }
        }
    }

    float bgl[4];
    #pragma unroll
    for (int fn = 0; fn < 4; ++fn) bgl[fn] = bg[norig(n0 + wn * 64 + fn * 16 + cl)];

    #pragma unroll
    for (int fm = 0; fm < 4; ++fm) {
        #pragma unroll
        for (int r = 0; r < 4; ++r) {
            const int m  = m0 + wm * 64 + fm * 16 + ch * 4 + r;
            const int b  = m >> 4;
            const int sl = m & 15;
            float* rowp = G + ((size_t)(rnn * CH + sl) * B_ + b) * G4H;
            #pragma unroll
            for (int fn = 0; fn < 4; ++fn)
                rowp[n0 + wn * 64 + fn * 16 + cl] = acc[fm][fn][r] + bgl[fn];
        }
    }
}

// ---------------------------------------------------------------------------
// Split Whh into bf16 hi/lo planes, rows in permuted n' order AND 16B-granule
// XOR-swizzled within each row: granule g stored at position g ^ (np & 15).
// The step kernel then stages with a PURE LINEAR copy and reads fragments
// conflict-free at pos = (ks*4+ch) ^ cl.
// ---------------------------------------------------------------------------
__global__ __launch_bounds__(64) void whh_split(
    const float* __restrict__ W, __bf16* __restrict__ hi, __bf16* __restrict__ lo)
{
    const int n  = blockIdx.x;                         // orig row: g*256 + j
    const int np = ((n & 255) >> 4) * 64 + (n >> 8) * 16 + (n & 15);
    const int t    = threadIdx.x;
    const int g    = t >> 1;                           // granule 0..31 (8 bf16)
    const int half = t & 1;
    const float4 v = *(const float4*)(W + (size_t)n * 256 + g * 8 + half * 4);
    bf16x4 h, l;
    split4(v, h, l);
    const int pos = g ^ (np & 15);
    *(bf16x4*)(hi + (size_t)np * 256 + pos * 8 + half * 4) = h;
    *(bf16x4*)(lo + (size_t)np * 256 + pos * 8 + half * 4) = l;
}

// ---------------------------------------------------------------------------
// One LSTM step. Grid (16 mg, 8 jsl) = 128 blocks x 256 thr (4 waves).
// Block: 32 m-rows (m = rnn*256+b, mg*32..) x 128 n' cols (jsl slice).
// Wave (mf, jg) owns 16m x 64n' = all 4 gates of 16 j's -> gate math is
// LANE-LOCAL: no transpose, one __syncthreads total. W hi/lo slice (128KB)
// staged by pure linear copy from pre-swizzled planes; B-frag ds_read_b128
// conflict-free via pos=(ks*4+ch)^cl. h ping-pongs in global fp32 across
// dispatches (kernel boundary = visibility); c read-modify-write in place.
// ---------------------------------------------------------------------------
__global__ __launch_bounds__(256) void lstm_np(
    const float* __restrict__ G,
    const __bf16* __restrict__ Whi, const __bf16* __restrict__ Wlo,
    const float* __restrict__ hin, float* __restrict__ hout,
    float* __restrict__ cst, float* __restrict__ sc,
    int sl, int s_glob, int first)
{
    __shared__ __align__(16) __bf16 Wl[2][128 * 256];   // 128 KB

    const int t   = threadIdx.x;
    const int mg  = blockIdx.x;      // 0..15 (m-rows mg*32..)
    const int jsl = blockIdx.y;      // 0..7  (n' slice jsl*128..)
    const int w   = t >> 6;
    const int l   = t & 63;
    const int cl  = l & 15;
    const int ch  = l >> 4;
    const int mf  = w >> 1;
    const int jg  = w & 1;
    const int rnn = mg >> 3;

    // ---- issue h loads (A rows, fragment k-layout) ----
    const float* hsrc = hin + (size_t)(mg * 32 + mf * 16 + cl) * 256;
    float4 hreg[16];
    #pragma unroll
    for (int ks = 0; ks < 8; ++ks) {
        hreg[2 * ks]     = *(const float4*)(hsrc + ks * 32 + ch * 8);
        hreg[2 * ks + 1] = *(const float4*)(hsrc + ks * 32 + ch * 8 + 4);
    }

    // ---- issue G loads ----
    float Gv[4][4];
    const float* Gb = G + ((size_t)(rnn * CH + sl) * B_ + ((mg & 7) * 32 + mf * 16)) * G4H
                    + jsl * 128 + jg * 64;
    #pragma unroll
    for (int g = 0; g < 4; ++g)
        #pragma unroll
        for (int r = 0; r < 4; ++r)
            Gv[g][r] = Gb[(size_t)(ch * 4 + r) * G4H + g * 16 + cl];

    // ---- c state ----
    const int jcol = jsl * 32 + jg * 16 + cl;
    float cv[4];
    if (first) {
        cv[0] = cv[1] = cv[2] = cv[3] = 0.f;
    } else {
        #pragma unroll
        for (int r = 0; r < 4; ++r)
            cv[r] = cst[(size_t)(mg * 32 + mf * 16 + ch * 4 + r) * 256 + jcol];
    }

    // ---- stage W slice: pure linear 128KB copy (pre-swizzled in memory) ----
    {
        const __bf16* sh = Whi + (size_t)jsl * 32768;
        const __bf16* slo = Wlo + (size_t)jsl * 32768;
        #pragma unroll
        for (int q = 0; q < 4; ++q) {
            bf16x8 th[4], tl[4];
            #pragma unroll
            for (int u = 0; u < 4; ++u) {
                const int gr = (q * 4 + u) * 256 + t;    // granule 0..4095
                th[u] = *(const bf16x8*)(sh + gr * 8);
                tl[u] = *(const bf16x8*)(slo + gr * 8);
            }
            #pragma unroll
            for (int u = 0; u < 4; ++u) {
                const int gr = (q * 4 + u) * 256 + t;
                *(bf16x8*)(&Wl[0][gr * 8]) = th[u];
                *(bf16x8*)(&Wl[1][gr * 8]) = tl[u];
            }
        }
    }

    // ---- convert h to A-frags while staging drains ----
    bf16x8 fAh[8], fAl[8];
    #pragma unroll
    for (int ks = 0; ks < 8; ++ks) {
        bf16x4 h0v, l0v, h1v, l1v;
        split4(hreg[2 * ks], h0v, l0v);
        split4(hreg[2 * ks + 1], h1v, l1v);
        fAh[ks] = __builtin_shufflevector(h0v, h1v, 0, 1, 2, 3, 4, 5, 6, 7);
        fAl[ks] = __builtin_shufflevector(l0v, l1v, 0, 1, 2, 3, 4, 5, 6, 7);
    }

    __syncthreads();

    // ---- MFMA: 8 ksub x (4 gates x 3 split passes) ----
    f32x4 acc[4];
    #pragma unroll
    for (int g = 0; g < 4; ++g) acc[g] = (f32x4){0.f, 0.f, 0.f, 0.f};

    #pragma unroll
    for (int ks = 0; ks < 8; ++ks) {
        bf16x8 fBh[4], fBl[4];
        #pragma unroll
        for (int g = 0; g < 4; ++g) {
            const int nploc = jg * 64 + g * 16 + cl;
            const int pos   = (ks * 4 + ch) ^ cl;
            const int off   = nploc * 256 + pos * 8;
            fBh[g] = *(const bf16x8*)(&Wl[0][off]);
            fBl[g] = *(const bf16x8*)(&Wl[1][off]);
        }
        #pragma unroll
        for (int g = 0; g < 4; ++g)
            acc[g] = __builtin_amdgcn_mfma_f32_16x16x32_bf16(fAh[ks], fBh[g], acc[g], 0, 0, 0);
        #pragma unroll
        for (int g = 0; g < 4; ++g)
            acc[g] = __builtin_amdgcn_mfma_f32_16x16x32_bf16(fAh[ks], fBl[g], acc[g], 0, 0, 0);
        #pragma unroll
        for (int g = 0; g < 4; ++g)
            acc[g] = __builtin_amdgcn_mfma_f32_16x16x32_bf16(fAl[ks], fBh[g], acc[g], 0, 0, 0);
    }

    // ---- lane-local gate math + state update ----
    #pragma unroll
    for (int r = 0; r < 4; ++r) {
        const float gi = acc[0][r] + Gv[0][r];
        const float gf = acc[1][r] + Gv[1][r];
        const float gg = acc[2][r] + Gv[2][r];
        const float go = acc[3][r] + Gv[3][r];
        const float c = sigf(gf) * cv[r] + sigf(gi) * tanhf(gg);
        const float h = sigf(go) * tanhf(c);
        const int m = mg * 32 + mf * 16 + ch * 4 + r;
        cst[(size_t)m * 256 + jcol] = c;
        hout[(size_t)m * 256 + jcol] = h;
        if (rnn == 0)
            sc[((size_t)m * S_ + s_glob) * H_ + jcol] = h;
    }
}

// ---------------------------------------------------------------------------
// Fused attention epilogue, one block per batch row b. r = final rnn1 h.
// ---------------------------------------------------------------------------
__global__ __launch_bounds__(256) void final_kernel(
    const float* __restrict__ sc, const float* __restrict__ r,
    const float* __restrict__ Wattn, const float* __restrict__ battn,
    const float* __restrict__ M, const float* __restrict__ bscal,
    const float* __restrict__ mask, float* __restrict__ out)
{
    __shared__ float rs[256], us[256], red[256], as_[256];
    const int b = blockIdx.x;
    const int t = threadIdx.x;

    rs[t] = r[(size_t)b * 256 + t];
    __syncthreads();

    float acc = 0.0f;
    for (int h = 0; h < 256; ++h) acc += rs[h] * Wattn[h * 256 + t];
    us[t] = acc;

    red[t] = battn[t] * rs[t];
    __syncthreads();
    for (int off = 128; off; off >>= 1) {
        if (t < off) red[t] += red[t + off];
        __syncthreads();
    }
    float beta = red[0];
    __syncthreads();

    float vh = 0.0f;
    {
        const float* Mrow = M + t * 256;
        for (int k = 0; k < 256; ++k) vh += Mrow[k] * rs[k];
    }

    float e = -INFINITY;
    if (t < S_) {
        float d = 0.0f;
        const float* scrow = sc + ((size_t)b * S_ + t) * H_;
        for (int h = 0; h < 256; ++h) d += scrow[h] * us[h];
        e = (d + beta) * mask[b * S_ + t];
    }
    red[t] = e;
    __syncthreads();
    for (int off = 128; off; off >>= 1) {
        if (t < off) red[t] = fmaxf(red[t], red[t + off]);
        __syncthreads();
    }
    float mx = red[0];
    __syncthreads();

    float p = (t < S_) ? expf(e - mx) : 0.0f;
    as_[t] = p;
    red[t] = p;
    __syncthreads();
    for (int off = 128; off; off >>= 1) {
        if (t < off) red[t] += red[t + off];
        __syncthreads();
    }
    float inv = 1.0f / red[0];
    __syncthreads();

    float ca = 0.0f;
    for (int s = 0; s < S_; ++s) ca += as_[s] * sc[((size_t)b * S_ + s) * H_ + t];
    ca *= inv;

    red[t] = ca * vh;
    __syncthreads();
    for (int off = 128; off; off >>= 1) {
        if (t < off) red[t] += red[t + off];
        __syncthreads();
    }
    if (t == 0) out[b] = red[0] + bscal[0];
}

// ---------------------------------------------------------------------------
extern "C" void kernel_launch(void* const* d_in, const int* in_sizes, int n_in,
                              void* d_out, int out_size, void* d_ws, size_t ws_size,
                              hipStream_t stream)
{
    const int*   x1    = (const int*)d_in[0];
    const int*   x2    = (const int*)d_in[1];
    const float* mask  = (const float*)d_in[2];
    const float* key_c = (const float*)d_in[3];
    const float* key_r = (const float*)d_in[4];
    const float* emb   = (const float*)d_in[5];
    const float* Wih   = (const float*)d_in[6];
    const float* Whh   = (const float*)d_in[7];
    const float* Wkh   = (const float*)d_in[8];
    const float* bg    = (const float*)d_in[9];
    const float* Wattn = (const float*)d_in[10];
    const float* battn = (const float*)d_in[11];
    const float* M     = (const float*)d_in[12];
    const float* bb    = (const float*)d_in[13];
    float* out = (float*)d_out;
    char*  wsb = (char*)d_ws;

    // byte layout
    float*  G    = (float*)(wsb + 0);            // 33,554,432
    float*  sc   = (float*)(wsb + 33554432);     // 41,943,040
    float*  h0   = (float*)(wsb + 75497472);     //    524,288
    float*  h1   = (float*)(wsb + 76021760);     //    524,288
    float*  cst  = (float*)(wsb + 76546048);     //    524,288
    __bf16* Whi  = (__bf16*)(wsb + 77070336);    //    524,288
    __bf16* Wlo  = (__bf16*)(wsb + 77594624);    //    524,288
    if (ws_size < 78118912) return;  // fail visibly if workspace too small

    hipMemsetAsync(h0, 0, 524288, stream);
    whh_split<<<dim3(1024), 64, 0, stream>>>(Whh, Whi, Wlo);

    for (int ci = 0; ci < NCH; ++ci) {
        gemm_g2<<<dim3(32, 8, 2), 256, 0, stream>>>(x1, x2, key_c, key_r, emb,
                                                    Wih, Wkh, bg, G, ci * CH);
        for (int slq = 0; slq < CH; ++slq) {
            const int s   = ci * CH + slq;
            const int par = s & 1;
            lstm_np<<<dim3(16, 8), 256, 0, stream>>>(G, Whi, Wlo,
                                                     par ? h1 : h0,
                                                     par ? h0 : h1,
                                                     cst, sc, slq, s, s == 0);
        }
    }

    // 160 steps (even) -> final h in h0; r = rnn1 rows
    final_kernel<<<dim3(256), 256, 0, stream>>>(sc, h0 + 65536, Wattn, battn,
                                                M, bb, mask, out);
}

// Round 9
// 1603.025 us; speedup vs baseline: 3.1784x; 1.1452x over previous
//
#include <hip/hip_runtime.h>
#include <math.h>

#define B_   256
#define S_   160
#define E_   300
#define H_   256
#define T_   200
#define G4H  1024
#define CH   16
#define NCH  10

typedef float  f32x4  __attribute__((ext_vector_type(4)));
typedef __bf16 bf16x4 __attribute__((ext_vector_type(4)));
typedef __bf16 bf16x8 __attribute__((ext_vector_type(8)));

__device__ __forceinline__ float sigf(float x) {
    float e = expf(-fabsf(x));
    float p = 1.0f / (1.0f + e);
    return x >= 0.0f ? p : e * p;
}

// permuted gate-col order: n' = (j>>4)*64 + g*16 + (j&15); orig row for n':
__device__ __forceinline__ int norig(int np) {
    return ((np >> 4) & 3) * 256 + ((np >> 6) << 4) + (np & 15);
}

// 4 consecutive K-values from concatenated [first(300) | second(200) | pad] row
__device__ __forceinline__ float4 pick4(const float* __restrict__ e,
                                        const float* __restrict__ k, int kg) {
    if (kg < E_)      return *(const float4*)(e + kg);
    if (kg < E_ + T_) return *(const float4*)(k + (kg - E_));
    return make_float4(0.f, 0.f, 0.f, 0.f);
}

__device__ __forceinline__ void split4(float4 v, bf16x4& h, bf16x4& l) {
    h[0] = (__bf16)v.x; l[0] = (__bf16)(v.x - (float)h[0]);
    h[1] = (__bf16)v.y; l[1] = (__bf16)(v.y - (float)h[1]);
    h[2] = (__bf16)v.z; l[2] = (__bf16)(v.z - (float)h[2]);
    h[3] = (__bf16)v.w; l[3] = (__bf16)(v.w - (float)h[3]);
}

// ---------------------------------------------------------------------------
// One-time weight prep: rows in permuted n' order, bf16 hi/lo planes.
//  - Whh  -> whh_hi/lo [np][256]        (plain rows: lstm reads frags direct)
//  - Wih||Wkh||pad -> wik_hi/lo [np][512] (concat cols, matches gemm k order)
// 1024 blocks x 128 threads.
// ---------------------------------------------------------------------------
__global__ __launch_bounds__(128) void prep_split(
    const float* __restrict__ Whh, const float* __restrict__ Wih,
    const float* __restrict__ Wkh,
    __bf16* __restrict__ whh_hi, __bf16* __restrict__ whh_lo,
    __bf16* __restrict__ wik_hi, __bf16* __restrict__ wik_lo)
{
    const int n  = blockIdx.x;                         // orig row: g*256 + j
    const int np = ((n & 255) >> 4) * 64 + (n >> 8) * 16 + (n & 15);
    const int t  = threadIdx.x;
    {
        const int k4 = t * 4;
        float4 v;
        if (k4 < E_)            v = *(const float4*)(Wih + (size_t)n * E_ + k4);
        else if (k4 < E_ + T_)  v = *(const float4*)(Wkh + (size_t)n * T_ + (k4 - E_));
        else                    v = make_float4(0.f, 0.f, 0.f, 0.f);
        bf16x4 h, l;
        split4(v, h, l);
        *(bf16x4*)(wik_hi + (size_t)np * 512 + k4) = h;
        *(bf16x4*)(wik_lo + (size_t)np * 512 + k4) = l;
    }
    if (t < 64) {
        const int k4 = t * 4;
        const float4 v = *(const float4*)(Whh + (size_t)n * 256 + k4);
        bf16x4 h, l;
        split4(v, h, l);
        *(bf16x4*)(whh_hi + (size_t)np * 256 + k4) = h;
        *(bf16x4*)(whh_lo + (size_t)np * 256 + k4) = l;
    }
}

// ---------------------------------------------------------------------------
// Input GEMM: split-bf16 MFMA, 128x128, BK=32. B from pre-split planes
// (pure bf16 copies, no VALU); A gathered+split in-kernel. n' outputs.
// ---------------------------------------------------------------------------
__global__ __launch_bounds__(256, 4) void gemm_g2(
    const int* __restrict__ x1, const int* __restrict__ x2,
    const float* __restrict__ key_c, const float* __restrict__ key_r,
    const float* __restrict__ emb,
    const __bf16* __restrict__ wik_hi, const __bf16* __restrict__ wik_lo,
    const float* __restrict__ bg,
    float* __restrict__ G, int s0)
{
    __shared__ __align__(16) __bf16 Ah[128 * 32];
    __shared__ __align__(16) __bf16 Al[128 * 32];
    __shared__ __align__(16) __bf16 Bh[128 * 32];
    __shared__ __align__(16) __bf16 Bl[128 * 32];

    const int t   = threadIdx.x;
    const int rnn = blockIdx.z;
    const int m0  = blockIdx.x * 128;
    const int n0  = blockIdx.y * 128;
    const int* xx = rnn ? x2 : x1;
    const float* key = rnn ? key_r : key_c;

    const int r0  = t >> 3;
    const int kq  = t & 7;
    const int csw = (((kq >> 1) ^ ((r0 >> 1) & 3)) * 16) + (kq & 1) * 8;

    const float* aeb[4]; const float* akb[4];
    const __bf16* wph[4]; const __bf16* wpl[4];
    #pragma unroll
    for (int i = 0; i < 4; ++i) {
        const int row = r0 + 32 * i;
        const int am  = m0 + row;
        const int bs  = (am >> 4) * S_ + s0 + (am & 15);
        aeb[i] = emb + (size_t)xx[bs] * E_;
        akb[i] = key + (size_t)bs * T_;
        wph[i] = wik_hi + (size_t)(n0 + row) * 512;
        wpl[i] = wik_lo + (size_t)(n0 + row) * 512;
    }

    const int w  = t >> 6;
    const int wm = w >> 1;
    const int wn = w & 1;
    const int l  = t & 63;
    const int cl = l & 15;
    const int ch = l >> 4;
    const int chs = ((ch ^ ((cl >> 1) & 3)) * 16);

    f32x4 acc[4][4];
    #pragma unroll
    for (int fm = 0; fm < 4; ++fm)
        #pragma unroll
        for (int fn = 0; fn < 4; ++fn) acc[fm][fn] = (f32x4){0.f, 0.f, 0.f, 0.f};

    for (int kt = 0; kt < 16; ++kt) {
        const int kg = kt * 32 + kq * 4;
        bf16x4 sAh[4], sAl[4], sBh[4], sBl[4];
        #pragma unroll
        for (int i = 0; i < 4; ++i) {
            const float4 va = pick4(aeb[i], akb[i], kg);
            split4(va, sAh[i], sAl[i]);
            sBh[i] = *(const bf16x4*)(wph[i] + kg);
            sBl[i] = *(const bf16x4*)(wpl[i] + kg);
        }
        __syncthreads();
        #pragma unroll
        for (int i = 0; i < 4; ++i) {
            const int off = (r0 + 32 * i) * 64 + csw;
            *(bf16x4*)((char*)Ah + off) = sAh[i];
            *(bf16x4*)((char*)Al + off) = sAl[i];
            *(bf16x4*)((char*)Bh + off) = sBh[i];
            *(bf16x4*)((char*)Bl + off) = sBl[i];
        }
        __syncthreads();

        bf16x8 fBh[4], fBl[4];
        #pragma unroll
        for (int fn = 0; fn < 4; ++fn) {
            const int off = (wn * 64 + fn * 16 + cl) * 64 + chs;
            fBh[fn] = *(const bf16x8*)((const char*)Bh + off);
            fBl[fn] = *(const bf16x8*)((const char*)Bl + off);
        }
        #pragma unroll
        for (int fm = 0; fm < 4; ++fm) {
            const int off = (wm * 64 + fm * 16 + cl) * 64 + chs;
            const bf16x8 fAh = *(const bf16x8*)((const char*)Ah + off);
            const bf16x8 fAl = *(const bf16x8*)((const char*)Al + off);
            #pragma unroll
            for (int fn = 0; fn < 4; ++fn) {
                acc[fm][fn] = __builtin_amdgcn_mfma_f32_16x16x32_bf16(fAh, fBh[fn], acc[fm][fn], 0, 0, 0);
                acc[fm][fn] = __builtin_amdgcn_mfma_f32_16x16x32_bf16(fAh, fBl[fn], acc[fm][fn], 0, 0, 0);
                acc[fm][fn] = __builtin_amdgcn_mfma_f32_16x16x32_bf16(fAl, fBh[fn], acc[fm][fn], 0, 0, 0);
            }
        }
    }

    float bgl[4];
    #pragma unroll
    for (int fn = 0; fn < 4; ++fn) bgl[fn] = bg[norig(n0 + wn * 64 + fn * 16 + cl)];

    #pragma unroll
    for (int fm = 0; fm < 4; ++fm) {
        #pragma unroll
        for (int r = 0; r < 4; ++r) {
            const int m  = m0 + wm * 64 + fm * 16 + ch * 4 + r;
            const int b  = m >> 4;
            const int sl = m & 15;
            float* rowp = G + ((size_t)(rnn * CH + sl) * B_ + b) * G4H;
            #pragma unroll
            for (int fn = 0; fn < 4; ++fn)
                rowp[n0 + wn * 64 + fn * 16 + cl] = acc[fm][fn][r] + bgl[fn];
        }
    }
}

// ---------------------------------------------------------------------------
// One LSTM step, K-split x4. Grid (32 mt, 16 jt) = 512 blocks x 256 thr
// (4 waves) = 2048 waves = 8/CU. Tile: 16 m-rows x 64 n' (16 j x 4 gates);
// wave w computes K-slice [w*64, w*64+64) -> 24 MFMA; partials reduced via
// LDS psum (stride 66, 2-way max); gate math lane-local (n' permutation).
// h state = bf16 hi/lo planes (no split VALU); W/A frags direct from global
// (L2-resident). One barrier total.
// ---------------------------------------------------------------------------
__global__ __launch_bounds__(256, 2) void lstm_ks(
    const float* __restrict__ G,
    const __bf16* __restrict__ Whi, const __bf16* __restrict__ Wlo,
    const __bf16* __restrict__ hhi_in, const __bf16* __restrict__ hlo_in,
    __bf16* __restrict__ hhi_out, __bf16* __restrict__ hlo_out,
    float* __restrict__ cst, float* __restrict__ sc,
    int sl, int s_glob, int first)
{
    __shared__ float ps[64 * 66];      // 16.9 KB

    const int t  = threadIdx.x;
    const int w  = t >> 6;
    const int l  = t & 63;
    const int cl = l & 15;
    const int ch = l >> 4;
    const int mt = blockIdx.x;         // 0..31
    const int jt = blockIdx.y;         // 0..15
    const int rnn = mt >> 4;
    const int b0  = (mt & 15) * 16;
    const int m0  = mt * 16;           // plane row base (= rnn*256 + b0)

    // ---- epilogue operands (independent; issue at entry) ----
    const int me = t >> 4;             // 0..15
    const int jl = t & 15;
    const int j  = jt * 16 + jl;
    float Ge[4];
    const float* Gb = G + ((size_t)(rnn * CH + sl) * B_ + b0 + me) * G4H + jt * 64;
    #pragma unroll
    for (int g = 0; g < 4; ++g) Ge[g] = Gb[g * 16 + jl];
    const float c_in = first ? 0.f : cst[(size_t)(m0 + me) * 256 + j];

    // ---- A frags (this wave's K-slice: ks = 2w, 2w+1) ----
    const size_t ab = (size_t)(m0 + cl) * 256 + w * 64 + ch * 8;
    const bf16x8 fAh0 = *(const bf16x8*)(hhi_in + ab);
    const bf16x8 fAh1 = *(const bf16x8*)(hhi_in + ab + 32);
    const bf16x8 fAl0 = *(const bf16x8*)(hlo_in + ab);
    const bf16x8 fAl1 = *(const bf16x8*)(hlo_in + ab + 32);

    // ---- B frags ----
    bf16x8 fBh[4][2], fBl[4][2];
    #pragma unroll
    for (int g = 0; g < 4; ++g) {
        const size_t bb = (size_t)(jt * 64 + g * 16 + cl) * 256 + w * 64 + ch * 8;
        fBh[g][0] = *(const bf16x8*)(Whi + bb);
        fBh[g][1] = *(const bf16x8*)(Whi + bb + 32);
        fBl[g][0] = *(const bf16x8*)(Wlo + bb);
        fBl[g][1] = *(const bf16x8*)(Wlo + bb + 32);
    }

    f32x4 acc[4];
    #pragma unroll
    for (int g = 0; g < 4; ++g) acc[g] = (f32x4){0.f, 0.f, 0.f, 0.f};
    #pragma unroll
    for (int g = 0; g < 4; ++g) {
        acc[g] = __builtin_amdgcn_mfma_f32_16x16x32_bf16(fAh0, fBh[g][0], acc[g], 0, 0, 0);
        acc[g] = __builtin_amdgcn_mfma_f32_16x16x32_bf16(fAh1, fBh[g][1], acc[g], 0, 0, 0);
        acc[g] = __builtin_amdgcn_mfma_f32_16x16x32_bf16(fAh0, fBl[g][0], acc[g], 0, 0, 0);
        acc[g] = __builtin_amdgcn_mfma_f32_16x16x32_bf16(fAh1, fBl[g][1], acc[g], 0, 0, 0);
        acc[g] = __builtin_amdgcn_mfma_f32_16x16x32_bf16(fAl0, fBh[g][0], acc[g], 0, 0, 0);
        acc[g] = __builtin_amdgcn_mfma_f32_16x16x32_bf16(fAl1, fBh[g][1], acc[g], 0, 0, 0);
    }

    // ---- psum to LDS ----
    #pragma unroll
    for (int g = 0; g < 4; ++g)
        #pragma unroll
        for (int r = 0; r < 4; ++r)
            ps[(w * 16 + ch * 4 + r) * 66 + g * 16 + cl] = acc[g][r];
    __syncthreads();

    // ---- reduce 4 K-slices + gate math (1 cell/thread) ----
    float g4[4];
    #pragma unroll
    for (int g = 0; g < 4; ++g) {
        float s = Ge[g];
        #pragma unroll
        for (int w2 = 0; w2 < 4; ++w2)
            s += ps[(w2 * 16 + me) * 66 + g * 16 + jl];
        g4[g] = s;
    }
    const float c = sigf(g4[1]) * c_in + sigf(g4[0]) * tanhf(g4[2]);
    const float h = sigf(g4[3]) * tanhf(c);
    cst[(size_t)(m0 + me) * 256 + j] = c;
    const __bf16 hh = (__bf16)h;
    const size_t ho = (size_t)(m0 + me) * 256 + j;
    hhi_out[ho] = hh;
    hlo_out[ho] = (__bf16)(h - (float)hh);
    if (rnn == 0)
        sc[((size_t)(b0 + me) * S_ + s_glob) * H_ + j] = h;
}

// ---------------------------------------------------------------------------
// Fused attention epilogue, one block per batch row b. r reconstructed from
// final h hi/lo planes (rnn1 rows = 256..511).
// ---------------------------------------------------------------------------
__global__ __launch_bounds__(256) void final_kernel(
    const float* __restrict__ sc,
    const __bf16* __restrict__ rhi, const __bf16* __restrict__ rlo,
    const float* __restrict__ Wattn, const float* __restrict__ battn,
    const float* __restrict__ M, const float* __restrict__ bscal,
    const float* __restrict__ mask, float* __restrict__ out)
{
    __shared__ float rs[256], us[256], red[256], as_[256];
    const int b = blockIdx.x;
    const int t = threadIdx.x;

    const size_t ri = (size_t)(256 + b) * 256 + t;
    rs[t] = (float)rhi[ri] + (float)rlo[ri];
    __syncthreads();

    float acc = 0.0f;
    for (int h = 0; h < 256; ++h) acc += rs[h] * Wattn[h * 256 + t];
    us[t] = acc;

    red[t] = battn[t] * rs[t];
    __syncthreads();
    for (int off = 128; off; off >>= 1) {
        if (t < off) red[t] += red[t + off];
        __syncthreads();
    }
    float beta = red[0];
    __syncthreads();

    float vh = 0.0f;
    {
        const float* Mrow = M + t * 256;
        for (int k = 0; k < 256; ++k) vh += Mrow[k] * rs[k];
    }

    float e = -INFINITY;
    if (t < S_) {
        float d = 0.0f;
        const float* scrow = sc + ((size_t)b * S_ + t) * H_;
        for (int h = 0; h < 256; ++h) d += scrow[h] * us[h];
        e = (d + beta) * mask[b * S_ + t];
    }
    red[t] = e;
    __syncthreads();
    for (int off = 128; off; off >>= 1) {
        if (t < off) red[t] = fmaxf(red[t], red[t + off]);
        __syncthreads();
    }
    float mx = red[0];
    __syncthreads();

    float p = (t < S_) ? expf(e - mx) : 0.0f;
    as_[t] = p;
    red[t] = p;
    __syncthreads();
    for (int off = 128; off; off >>= 1) {
        if (t < off) red[t] += red[t + off];
        __syncthreads();
    }
    float inv = 1.0f / red[0];
    __syncthreads();

    float ca = 0.0f;
    for (int s = 0; s < S_; ++s) ca += as_[s] * sc[((size_t)b * S_ + s) * H_ + t];
    ca *= inv;

    red[t] = ca * vh;
    __syncthreads();
    for (int off = 128; off; off >>= 1) {
        if (t < off) red[t] += red[t + off];
        __syncthreads();
    }
    if (t == 0) out[b] = red[0] + bscal[0];
}

// ---------------------------------------------------------------------------
extern "C" void kernel_launch(void* const* d_in, const int* in_sizes, int n_in,
                              void* d_out, int out_size, void* d_ws, size_t ws_size,
                              hipStream_t stream)
{
    const int*   x1    = (const int*)d_in[0];
    const int*   x2    = (const int*)d_in[1];
    const float* mask  = (const float*)d_in[2];
    const float* key_c = (const float*)d_in[3];
    const float* key_r = (const float*)d_in[4];
    const float* emb   = (const float*)d_in[5];
    const float* Wih   = (const float*)d_in[6];
    const float* Whh   = (const float*)d_in[7];
    const float* Wkh   = (const float*)d_in[8];
    const float* bg    = (const float*)d_in[9];
    const float* Wattn = (const float*)d_in[10];
    const float* battn = (const float*)d_in[11];
    const float* M     = (const float*)d_in[12];
    const float* bb    = (const float*)d_in[13];
    float* out = (float*)d_out;
    char*  wsb = (char*)d_ws;

    // byte layout
    float*  G     = (float*)(wsb + 0);            // 33,554,432
    float*  sc    = (float*)(wsb + 33554432);     // 41,943,040
    __bf16* hhi0  = (__bf16*)(wsb + 75497472);    //    262,144
    __bf16* hlo0  = (__bf16*)(wsb + 75759616);    //    262,144
    __bf16* hhi1  = (__bf16*)(wsb + 76021760);    //    262,144
    __bf16* hlo1  = (__bf16*)(wsb + 76283904);    //    262,144
    float*  cst   = (float*)(wsb + 76546048);     //    524,288
    __bf16* WhhHi = (__bf16*)(wsb + 77070336);    //    524,288
    __bf16* WhhLo = (__bf16*)(wsb + 77594624);    //    524,288
    __bf16* WikHi = (__bf16*)(wsb + 78118912);    //  1,048,576
    __bf16* WikLo = (__bf16*)(wsb + 79167488);    //  1,048,576
    if (ws_size < 80216064) return;  // fail visibly if workspace too small

    // zero parity-0 h planes (hhi0+hlo0 contiguous)
    hipMemsetAsync(hhi0, 0, 524288, stream);
    prep_split<<<dim3(1024), 128, 0, stream>>>(Whh, Wih, Wkh,
                                               WhhHi, WhhLo, WikHi, WikLo);

    for (int ci = 0; ci < NCH; ++ci) {
        gemm_g2<<<dim3(32, 8, 2), 256, 0, stream>>>(x1, x2, key_c, key_r, emb,
                                                    WikHi, WikLo, bg, G, ci * CH);
        for (int slq = 0; slq < CH; ++slq) {
            const int s   = ci * CH + slq;
            const int par = s & 1;
            lstm_ks<<<dim3(32, 16), 256, 0, stream>>>(G, WhhHi, WhhLo,
                                                      par ? hhi1 : hhi0,
                                                      par ? hlo1 : hlo0,
                                                      par ? hhi0 : hhi1,
                                                      par ? hlo0 : hlo1,
                                                      cst, sc, slq, s, s == 0);
        }
    }

    // 160 steps (even) -> final h in plane 0; r = rnn1 rows
    final_kernel<<<dim3(256), 256, 0, stream>>>(sc, hhi0, hlo0, Wattn, battn,
                                                M, bb, mask, out);
}

// Round 10
// 1507.685 us; speedup vs baseline: 3.3794x; 1.0632x over previous
//
#include <hip/hip_runtime.h>
#include <math.h>

#define B_   256
#define S_   160
#define E_   300
#define H_   256
#define T_   200
#define G4H  1024
#define CH   16
#define NCH  10

typedef float  f32x4  __attribute__((ext_vector_type(4)));
typedef __bf16 bf16x4 __attribute__((ext_vector_type(4)));
typedef __bf16 bf16x8 __attribute__((ext_vector_type(8)));

__device__ __forceinline__ float sigf(float x) {
    float e = expf(-fabsf(x));
    float p = 1.0f / (1.0f + e);
    return x >= 0.0f ? p : e * p;
}

// permuted gate-col order: n' = (j>>4)*64 + g*16 + (j&15); orig row for n':
__device__ __forceinline__ int norig(int np) {
    return ((np >> 4) & 3) * 256 + ((np >> 6) << 4) + (np & 15);
}

// 4 consecutive K-values from concatenated [first(300) | second(200) | pad] row
__device__ __forceinline__ float4 pick4(const float* __restrict__ e,
                                        const float* __restrict__ k, int kg) {
    if (kg < E_)      return *(const float4*)(e + kg);
    if (kg < E_ + T_) return *(const float4*)(k + (kg - E_));
    return make_float4(0.f, 0.f, 0.f, 0.f);
}

__device__ __forceinline__ void split4(float4 v, bf16x4& h, bf16x4& l) {
    h[0] = (__bf16)v.x; l[0] = (__bf16)(v.x - (float)h[0]);
    h[1] = (__bf16)v.y; l[1] = (__bf16)(v.y - (float)h[1]);
    h[2] = (__bf16)v.z; l[2] = (__bf16)(v.z - (float)h[2]);
    h[3] = (__bf16)v.w; l[3] = (__bf16)(v.w - (float)h[3]);
}

// ---------------------------------------------------------------------------
// One-time weight prep: rows in permuted n' order, bf16 hi/lo planes.
// ---------------------------------------------------------------------------
__global__ __launch_bounds__(128) void prep_split(
    const float* __restrict__ Whh, const float* __restrict__ Wih,
    const float* __restrict__ Wkh,
    __bf16* __restrict__ whh_hi, __bf16* __restrict__ whh_lo,
    __bf16* __restrict__ wik_hi, __bf16* __restrict__ wik_lo)
{
    const int n  = blockIdx.x;                         // orig row: g*256 + j
    const int np = ((n & 255) >> 4) * 64 + (n >> 8) * 16 + (n & 15);
    const int t  = threadIdx.x;
    {
        const int k4 = t * 4;
        float4 v;
        if (k4 < E_)            v = *(const float4*)(Wih + (size_t)n * E_ + k4);
        else if (k4 < E_ + T_)  v = *(const float4*)(Wkh + (size_t)n * T_ + (k4 - E_));
        else                    v = make_float4(0.f, 0.f, 0.f, 0.f);
        bf16x4 h, l;
        split4(v, h, l);
        *(bf16x4*)(wik_hi + (size_t)np * 512 + k4) = h;
        *(bf16x4*)(wik_lo + (size_t)np * 512 + k4) = l;
    }
    if (t < 64) {
        const int k4 = t * 4;
        const float4 v = *(const float4*)(Whh + (size_t)n * 256 + k4);
        bf16x4 h, l;
        split4(v, h, l);
        *(bf16x4*)(whh_hi + (size_t)np * 256 + k4) = h;
        *(bf16x4*)(whh_lo + (size_t)np * 256 + k4) = l;
    }
}

// ---------------------------------------------------------------------------
// Input GEMM: split-bf16 MFMA, tile 128x128, BK=32, 512 threads = 8 waves
// (wave tile 64x32, acc 4x2). 2 blocks/CU -> 16 waves/CU for latency hiding.
// LDS layout + XOR swizzle identical to the proven 4-wave version; staging:
// each thread owns one row x 8 contiguous k's (one 16B write per plane).
// ---------------------------------------------------------------------------
__global__ __launch_bounds__(512, 2) void gemm_g2(
    const int* __restrict__ x1, const int* __restrict__ x2,
    const float* __restrict__ key_c, const float* __restrict__ key_r,
    const float* __restrict__ emb,
    const __bf16* __restrict__ wik_hi, const __bf16* __restrict__ wik_lo,
    const float* __restrict__ bg,
    float* __restrict__ G, int s0)
{
    __shared__ __align__(16) __bf16 Ah[128 * 32];
    __shared__ __align__(16) __bf16 Al[128 * 32];
    __shared__ __align__(16) __bf16 Bh[128 * 32];
    __shared__ __align__(16) __bf16 Bl[128 * 32];

    const int t   = threadIdx.x;
    const int rnn = blockIdx.z;
    const int m0  = blockIdx.x * 128;
    const int n0  = blockIdx.y * 128;
    const int* xx = rnn ? x2 : x1;
    const float* key = rnn ? key_r : key_c;

    // staging: row r0 = t>>2 (0..127), 16B chunk pair cq = t&3 (k = cq*8..cq*8+7)
    const int r0 = t >> 2;
    const int cq = t & 3;
    const int csw = ((cq ^ ((r0 >> 1) & 3)) * 16);   // swizzled 16B chunk offset

    const float* aeb; const float* akb;
    const __bf16* wph; const __bf16* wpl;
    {
        const int am = m0 + r0;
        const int bs = (am >> 4) * S_ + s0 + (am & 15);
        aeb = emb + (size_t)xx[bs] * E_;
        akb = key + (size_t)bs * T_;
        wph = wik_hi + (size_t)(n0 + r0) * 512;
        wpl = wik_lo + (size_t)(n0 + r0) * 512;
    }

    const int w  = t >> 6;       // 0..7
    const int wm = w >> 2;       // 0..1  (64-row half)
    const int wn = w & 3;        // 0..3  (32-col quarter)
    const int l  = t & 63;
    const int cl = l & 15;
    const int ch = l >> 4;
    const int chs = ((ch ^ ((cl >> 1) & 3)) * 16);

    f32x4 acc[4][2];
    #pragma unroll
    for (int fm = 0; fm < 4; ++fm)
        #pragma unroll
        for (int fn = 0; fn < 2; ++fn) acc[fm][fn] = (f32x4){0.f, 0.f, 0.f, 0.f};

    for (int kt = 0; kt < 16; ++kt) {
        const int kg = kt * 32 + cq * 8;
        const float4 va0 = pick4(aeb, akb, kg);
        const float4 va1 = pick4(aeb, akb, kg + 4);
        const bf16x8 vbh = *(const bf16x8*)(wph + kg);
        const bf16x8 vbl = *(const bf16x8*)(wpl + kg);
        bf16x4 h0, l0, h1, l1;
        split4(va0, h0, l0);
        split4(va1, h1, l1);
        const bf16x8 sah = __builtin_shufflevector(h0, h1, 0, 1, 2, 3, 4, 5, 6, 7);
        const bf16x8 sal = __builtin_shufflevector(l0, l1, 0, 1, 2, 3, 4, 5, 6, 7);
        __syncthreads();
        {
            const int off = r0 * 64 + csw;
            *(bf16x8*)((char*)Ah + off) = sah;
            *(bf16x8*)((char*)Al + off) = sal;
            *(bf16x8*)((char*)Bh + off) = vbh;
            *(bf16x8*)((char*)Bl + off) = vbl;
        }
        __syncthreads();

        bf16x8 fBh[2], fBl[2];
        #pragma unroll
        for (int fn = 0; fn < 2; ++fn) {
            const int off = (wn * 32 + fn * 16 + cl) * 64 + chs;
            fBh[fn] = *(const bf16x8*)((const char*)Bh + off);
            fBl[fn] = *(const bf16x8*)((const char*)Bl + off);
        }
        #pragma unroll
        for (int fm = 0; fm < 4; ++fm) {
            const int off = (wm * 64 + fm * 16 + cl) * 64 + chs;
            const bf16x8 fAh = *(const bf16x8*)((const char*)Ah + off);
            const bf16x8 fAl = *(const bf16x8*)((const char*)Al + off);
            #pragma unroll
            for (int fn = 0; fn < 2; ++fn) {
                acc[fm][fn] = __builtin_amdgcn_mfma_f32_16x16x32_bf16(fAh, fBh[fn], acc[fm][fn], 0, 0, 0);
                acc[fm][fn] = __builtin_amdgcn_mfma_f32_16x16x32_bf16(fAh, fBl[fn], acc[fm][fn], 0, 0, 0);
                acc[fm][fn] = __builtin_amdgcn_mfma_f32_16x16x32_bf16(fAl, fBh[fn], acc[fm][fn], 0, 0, 0);
            }
        }
    }

    float bgl[2];
    #pragma unroll
    for (int fn = 0; fn < 2; ++fn)
        bgl[fn] = bg[norig(n0 + wn * 32 + fn * 16 + cl)];

    #pragma unroll
    for (int fm = 0; fm < 4; ++fm) {
        #pragma unroll
        for (int r = 0; r < 4; ++r) {
            const int m  = m0 + wm * 64 + fm * 16 + ch * 4 + r;
            const int b  = m >> 4;
            const int sl = m & 15;
            float* rowp = G + ((size_t)(rnn * CH + sl) * B_ + b) * G4H;
            #pragma unroll
            for (int fn = 0; fn < 2; ++fn)
                rowp[n0 + wn * 32 + fn * 16 + cl] = acc[fm][fn][r] + bgl[fn];
        }
    }
}

// ---------------------------------------------------------------------------
// One LSTM step, K-split x8. Grid (32 mt, 16 jt) = 512 blocks x 512 thr
// (8 waves) = 4096 waves = 16/CU. Wave w: K-slice [w*32, w*32+32) of the
// 16m x 64n' tile -> 12 MFMA (4 independent 3-chains). Partials reduced via
// LDS; gate math lane-local (n' permutation); h = bf16 hi/lo planes.
// ---------------------------------------------------------------------------
__global__ __launch_bounds__(512, 2) void lstm_ks(
    const float* __restrict__ G,
    const __bf16* __restrict__ Whi, const __bf16* __restrict__ Wlo,
    const __bf16* __restrict__ hhi_in, const __bf16* __restrict__ hlo_in,
    __bf16* __restrict__ hhi_out, __bf16* __restrict__ hlo_out,
    float* __restrict__ cst, float* __restrict__ sc,
    int sl, int s_glob, int first)
{
    __shared__ float ps[128 * 66];     // 33.8 KB

    const int t  = threadIdx.x;
    const int w  = t >> 6;             // 0..7 (K-slice)
    const int l  = t & 63;
    const int cl = l & 15;
    const int ch = l >> 4;
    const int mt = blockIdx.x;         // 0..31
    const int jt = blockIdx.y;         // 0..15
    const int rnn = mt >> 4;
    const int b0  = (mt & 15) * 16;
    const int m0  = mt * 16;           // plane row base (= rnn*256 + b0)

    // ---- epilogue operands (threads 0..255; independent, issue at entry) ----
    const int me = (t >> 4) & 15;
    const int jl = t & 15;
    const int j  = jt * 16 + jl;
    float Ge[4];
    float c_in = 0.f;
    if (t < 256) {
        const float* Gb = G + ((size_t)(rnn * CH + sl) * B_ + b0 + me) * G4H + jt * 64;
        #pragma unroll
        for (int g = 0; g < 4; ++g) Ge[g] = Gb[g * 16 + jl];
        if (!first) c_in = cst[(size_t)(m0 + me) * 256 + j];
    }

    // ---- A frags (this wave's K-slice w*32) ----
    const size_t ab = (size_t)(m0 + cl) * 256 + w * 32 + ch * 8;
    const bf16x8 fAh = *(const bf16x8*)(hhi_in + ab);
    const bf16x8 fAl = *(const bf16x8*)(hlo_in + ab);

    // ---- B frags ----
    bf16x8 fBh[4], fBl[4];
    #pragma unroll
    for (int g = 0; g < 4; ++g) {
        const size_t bb = (size_t)(jt * 64 + g * 16 + cl) * 256 + w * 32 + ch * 8;
        fBh[g] = *(const bf16x8*)(Whi + bb);
        fBl[g] = *(const bf16x8*)(Wlo + bb);
    }

    f32x4 acc[4];
    #pragma unroll
    for (int g = 0; g < 4; ++g) acc[g] = (f32x4){0.f, 0.f, 0.f, 0.f};
    #pragma unroll
    for (int g = 0; g < 4; ++g) {
        acc[g] = __builtin_amdgcn_mfma_f32_16x16x32_bf16(fAh, fBh[g], acc[g], 0, 0, 0);
        acc[g] = __builtin_amdgcn_mfma_f32_16x16x32_bf16(fAh, fBl[g], acc[g], 0, 0, 0);
        acc[g] = __builtin_amdgcn_mfma_f32_16x16x32_bf16(fAl, fBh[g], acc[g], 0, 0, 0);
    }

    // ---- psum to LDS ----
    #pragma unroll
    for (int g = 0; g < 4; ++g)
        #pragma unroll
        for (int r = 0; r < 4; ++r)
            ps[(w * 16 + ch * 4 + r) * 66 + g * 16 + cl] = acc[g][r];
    __syncthreads();

    // ---- reduce 8 K-slices + gate math (threads 0..255, 1 cell each) ----
    if (t < 256) {
        float g4[4];
        #pragma unroll
        for (int g = 0; g < 4; ++g) {
            float s = Ge[g];
            #pragma unroll
            for (int w2 = 0; w2 < 8; ++w2)
                s += ps[(w2 * 16 + me) * 66 + g * 16 + jl];
            g4[g] = s;
        }
        const float c = sigf(g4[1]) * c_in + sigf(g4[0]) * tanhf(g4[2]);
        const float h = sigf(g4[3]) * tanhf(c);
        cst[(size_t)(m0 + me) * 256 + j] = c;
        const __bf16 hh = (__bf16)h;
        const size_t ho = (size_t)(m0 + me) * 256 + j;
        hhi_out[ho] = hh;
        hlo_out[ho] = (__bf16)(h - (float)hh);
        if (rnn == 0)
            sc[((size_t)(b0 + me) * S_ + s_glob) * H_ + j] = h;
    }
}

// ---------------------------------------------------------------------------
// Fused attention epilogue, one block per batch row b. r reconstructed from
// final h hi/lo planes (rnn1 rows = 256..511).
// ---------------------------------------------------------------------------
__global__ __launch_bounds__(256) void final_kernel(
    const float* __restrict__ sc,
    const __bf16* __restrict__ rhi, const __bf16* __restrict__ rlo,
    const float* __restrict__ Wattn, const float* __restrict__ battn,
    const float* __restrict__ M, const float* __restrict__ bscal,
    const float* __restrict__ mask, float* __restrict__ out)
{
    __shared__ float rs[256], us[256], red[256], as_[256];
    const int b = blockIdx.x;
    const int t = threadIdx.x;

    const size_t ri = (size_t)(256 + b) * 256 + t;
    rs[t] = (float)rhi[ri] + (float)rlo[ri];
    __syncthreads();

    float acc = 0.0f;
    for (int h = 0; h < 256; ++h) acc += rs[h] * Wattn[h * 256 + t];
    us[t] = acc;

    red[t] = battn[t] * rs[t];
    __syncthreads();
    for (int off = 128; off; off >>= 1) {
        if (t < off) red[t] += red[t + off];
        __syncthreads();
    }
    float beta = red[0];
    __syncthreads();

    float vh = 0.0f;
    {
        const float* Mrow = M + t * 256;
        for (int k = 0; k < 256; ++k) vh += Mrow[k] * rs[k];
    }

    float e = -INFINITY;
    if (t < S_) {
        float d = 0.0f;
        const float* scrow = sc + ((size_t)b * S_ + t) * H_;
        for (int h = 0; h < 256; ++h) d += scrow[h] * us[h];
        e = (d + beta) * mask[b * S_ + t];
    }
    red[t] = e;
    __syncthreads();
    for (int off = 128; off; off >>= 1) {
        if (t < off) red[t] = fmaxf(red[t], red[t + off]);
        __syncthreads();
    }
    float mx = red[0];
    __syncthreads();

    float p = (t < S_) ? expf(e - mx) : 0.0f;
    as_[t] = p;
    red[t] = p;
    __syncthreads();
    for (int off = 128; off; off >>= 1) {
        if (t < off) red[t] += red[t + off];
        __syncthreads();
    }
    float inv = 1.0f / red[0];
    __syncthreads();

    float ca = 0.0f;
    for (int s = 0; s < S_; ++s) ca += as_[s] * sc[((size_t)b * S_ + s) * H_ + t];
    ca *= inv;

    red[t] = ca * vh;
    __syncthreads();
    for (int off = 128; off; off >>= 1) {
        if (t < off) red[t] += red[t + off];
        __syncthreads();
    }
    if (t == 0) out[b] = red[0] + bscal[0];
}

// ---------------------------------------------------------------------------
extern "C" void kernel_launch(void* const* d_in, const int* in_sizes, int n_in,
                              void* d_out, int out_size, void* d_ws, size_t ws_size,
                              hipStream_t stream)
{
    const int*   x1    = (const int*)d_in[0];
    const int*   x2    = (const int*)d_in[1];
    const float* mask  = (const float*)d_in[2];
    const float* key_c = (const float*)d_in[3];
    const float* key_r = (const float*)d_in[4];
    const float* emb   = (const float*)d_in[5];
    const float* Wih   = (const float*)d_in[6];
    const float* Whh   = (const float*)d_in[7];
    const float* Wkh   = (const float*)d_in[8];
    const float* bg    = (const float*)d_in[9];
    const float* Wattn = (const float*)d_in[10];
    const float* battn = (const float*)d_in[11];
    const float* M     = (const float*)d_in[12];
    const float* bb    = (const float*)d_in[13];
    float* out = (float*)d_out;
    char*  wsb = (char*)d_ws;

    // byte layout
    float*  G     = (float*)(wsb + 0);            // 33,554,432
    float*  sc    = (float*)(wsb + 33554432);     // 41,943,040
    __bf16* hhi0  = (__bf16*)(wsb + 75497472);    //    262,144
    __bf16* hlo0  = (__bf16*)(wsb + 75759616);    //    262,144
    __bf16* hhi1  = (__bf16*)(wsb + 76021760);    //    262,144
    __bf16* hlo1  = (__bf16*)(wsb + 76283904);    //    262,144
    float*  cst   = (float*)(wsb + 76546048);     //    524,288
    __bf16* WhhHi = (__bf16*)(wsb + 77070336);    //    524,288
    __bf16* WhhLo = (__bf16*)(wsb + 77594624);    //    524,288
    __bf16* WikHi = (__bf16*)(wsb + 78118912);    //  1,048,576
    __bf16* WikLo = (__bf16*)(wsb + 79167488);    //  1,048,576
    if (ws_size < 80216064) return;  // fail visibly if workspace too small

    // zero parity-0 h planes (hhi0+hlo0 contiguous)
    hipMemsetAsync(hhi0, 0, 524288, stream);
    prep_split<<<dim3(1024), 128, 0, stream>>>(Whh, Wih, Wkh,
                                               WhhHi, WhhLo, WikHi, WikLo);

    for (int ci = 0; ci < NCH; ++ci) {
        gemm_g2<<<dim3(32, 8, 2), 512, 0, stream>>>(x1, x2, key_c, key_r, emb,
                                                    WikHi, WikLo, bg, G, ci * CH);
        for (int slq = 0; slq < CH; ++slq) {
            const int s   = ci * CH + slq;
            const int par = s & 1;
            lstm_ks<<<dim3(32, 16), 512, 0, stream>>>(G, WhhHi, WhhLo,
                                                      par ? hhi1 : hhi0,
                                                      par ? hlo1 : hlo0,
                                                      par ? hhi0 : hhi1,
                                                      par ? hlo0 : hlo1,
                                                      cst, sc, slq, s, s == 0);
        }
    }

    // 160 steps (even) -> final h in plane 0; r = rnn1 rows
    final_kernel<<<dim3(256), 256, 0, stream>>>(sc, hhi0, hlo0, Wattn, battn,
                                                M, bb, mask, out);
}